// Round 11
// baseline (48.118 us; speedup 1.0000x reference)
//
#include <hip/hip_runtime.h>
#include <hip/hip_bf16.h>

// RisingTideAttentionV2: out[m,:] = norm( exp(-||x_m - p_n|| / efft_n) ) @ V
// M=16384, N=4096, D=128. d2 = x2[m] + p2[n] - 2*dot(x_m,p_n). NEURON_SCALE=0.05125
//
// Screen: w = exp2f(sqrtf(d2)*cg) (cg<0) is EXACTLY 0.0f when sqrt(d2)*cg <=
// -151. pc[n] = p2[n] - thr2[n], thr = 154*efft*ln2 (margin absorbs rounding).
// All-e>=0 (one wave vote at the end) => every weight is exactly 0 => tile
// contributes 0 to numerator AND denominator => skip. Non-finite inputs are
// detected in PREP (global anomaly flag) -> forces the exact cold path.
//
// r11: BLOCK SWARM. r7-r10 showed main ~22us regardless of intra-block sync
// structure -- resident waves don't cover each other's latency. So get
// overlap from block TURNOVER instead: 8192 short-lived 2-wave blocks
// (64 rows x 128 cols each), 8 resident/CU, launch-pipelined so fresh blocks'
// staging/pf prologues overlap older blocks' compute. nb-major grid order =>
// consecutive blocks on a CU share P-columns (pf L1-hot) while streaming
// different X panels.

typedef __attribute__((ext_vector_type(8))) short short8;
typedef __attribute__((ext_vector_type(4))) float f32x4;

#define MTOT 16384
#define NTOT 4096
#define DD   128

__device__ __forceinline__ short f2bf(float f) {
    unsigned u = __float_as_uint(f);
    unsigned r = (u + 0x7fffu + ((u >> 16) & 1u)) >> 16;
    return (short)r;
}

// ---------------- prep ----------------
// blocks 0..1023:    X -> bf16 Xb + x2g (16 rows each)
// blocks 1024..1279: pos/val/temp -> Pb, p2g, cg, pcg, Vt (16 n each)
// blocks 1280..1791: zero d_out (16 KB each)
// blocks 1792..1795: zero rsum_g; block 1792 zeroes aflag
__global__ __launch_bounds__(256) void tide_prep(
    const float* __restrict__ x, const float* __restrict__ pos,
    const float* __restrict__ val, const float* __restrict__ temp,
    short* __restrict__ Xb, float* __restrict__ x2g,
    short* __restrict__ Pb, float* __restrict__ p2g, float* __restrict__ cg,
    float* __restrict__ pcg, short* __restrict__ Vt,
    float* __restrict__ outz, float* __restrict__ rsz, int* __restrict__ aflag)
{
    const int bid = blockIdx.x, tid = threadIdx.x;
    if (bid < 1024) {
        const int r = tid >> 4, sub = tid & 15;
        const int row = bid * 16 + r;
        const float* src = x + (size_t)row * DD + sub * 8;
        f32x4 a0 = ((const f32x4*)src)[0];
        f32x4 a1 = ((const f32x4*)src)[1];
        short8 h;
        h[0]=f2bf(a0[0]); h[1]=f2bf(a0[1]); h[2]=f2bf(a0[2]); h[3]=f2bf(a0[3]);
        h[4]=f2bf(a1[0]); h[5]=f2bf(a1[1]); h[6]=f2bf(a1[2]); h[7]=f2bf(a1[3]);
        *(short8*)(Xb + (size_t)row * DD + sub * 8) = h;
        float s = a0[0]*a0[0]+a0[1]*a0[1]+a0[2]*a0[2]+a0[3]*a0[3]
                + a1[0]*a1[0]+a1[1]*a1[1]+a1[2]*a1[2]+a1[3]*a1[3];
        s += __shfl_xor(s, 1); s += __shfl_xor(s, 2);
        s += __shfl_xor(s, 4); s += __shfl_xor(s, 8);
        if (sub == 0) {
            x2g[row] = s;
            if (!isfinite(s)) atomicOr(aflag, 1);
        }
    } else if (bid < 1280) {
        __shared__ short ldsv[16][132];
        const int r = tid >> 4, sub = tid & 15;
        const int n0 = (bid - 1024) * 16;
        const int n = n0 + r;
        const float* ps = pos + (size_t)n * DD + sub * 8;
        f32x4 a0 = ((const f32x4*)ps)[0];
        f32x4 a1 = ((const f32x4*)ps)[1];
        short8 h;
        h[0]=f2bf(a0[0]); h[1]=f2bf(a0[1]); h[2]=f2bf(a0[2]); h[3]=f2bf(a0[3]);
        h[4]=f2bf(a1[0]); h[5]=f2bf(a1[1]); h[6]=f2bf(a1[2]); h[7]=f2bf(a1[3]);
        *(short8*)(Pb + (size_t)n * DD + sub * 8) = h;
        float s = a0[0]*a0[0]+a0[1]*a0[1]+a0[2]*a0[2]+a0[3]*a0[3]
                + a1[0]*a1[0]+a1[1]*a1[1]+a1[2]*a1[2]+a1[3]*a1[3];
        s += __shfl_xor(s, 1); s += __shfl_xor(s, 2);
        s += __shfl_xor(s, 4); s += __shfl_xor(s, 8);
        const float* vs = val + (size_t)n * DD + sub * 8;
        f32x4 b0 = ((const f32x4*)vs)[0];
        f32x4 b1 = ((const f32x4*)vs)[1];
        if (sub == 0) {
            p2g[n] = s;
            float efft = (fabsf(temp[n]) + 0.1f) * 0.05125f;
            cg[n] = -1.4426950408889634f / efft;  // exp(-d/efft)=exp2(d*cg)
            float thr = 154.0f * efft * 0.6931471805599453f;
            float pcv = s - thr * thr;            // p2 - thr2
            pcg[n] = pcv;
            if (!isfinite(s) || !isfinite(cg[n]) || !isfinite(pcv))
                atomicOr(aflag, 1);
        }
        float vchk = b0[0]+b0[1]+b0[2]+b0[3]+b1[0]+b1[1]+b1[2]+b1[3];
        if (!isfinite(vchk)) atomicOr(aflag, 1);
        short* dstv = &ldsv[r][sub * 8];
        dstv[0]=f2bf(b0[0]); dstv[1]=f2bf(b0[1]); dstv[2]=f2bf(b0[2]); dstv[3]=f2bf(b0[3]);
        dstv[4]=f2bf(b1[0]); dstv[5]=f2bf(b1[1]); dstv[6]=f2bf(b1[2]); dstv[7]=f2bf(b1[3]);
        __syncthreads();
        const int d = tid >> 1, half = tid & 1;
        short8 t0;
        #pragma unroll
        for (int j = 0; j < 8; ++j) t0[j] = ldsv[half * 8 + j][d];
        *(short8*)(Vt + (size_t)d * NTOT + n0 + half * 8) = t0;
    } else if (bid < 1792) {
        f32x4 z = {0.f, 0.f, 0.f, 0.f};
        float* dst = outz + (size_t)(bid - 1280) * 4096;
        #pragma unroll
        for (int j = 0; j < 4; ++j)
            *(f32x4*)(dst + (size_t)(tid + 256 * j) * 4) = z;
    } else {
        f32x4 z = {0.f, 0.f, 0.f, 0.f};
        float* dst = rsz + (size_t)(bid - 1792) * 4096;
        #pragma unroll
        for (int j = 0; j < 4; ++j)
            *(f32x4*)(dst + (size_t)(tid + 256 * j) * 4) = z;
        if (bid == 1792 && tid == 0) aflag[0] = 0;
    }
}

// ---------------- main: block swarm ----------------
// grid = 8192, nb-major: blockIdx = nb*256 + mr. Block: rows mr*64..+63,
// cols nb*128..+127. 2 waves; wave w owns 64 cols at nb*128 + w*64.
// 16 KB panel staged once; 4 zero-sync subtiles; 8 blocks/CU resident.
__global__ __launch_bounds__(128, 4) void tide_main(
    const short* __restrict__ Xb, const float* __restrict__ x2g,
    const short* __restrict__ Pb, const float* __restrict__ p2g,
    const float* __restrict__ cg, const float* __restrict__ pcg,
    const short* __restrict__ Vt,
    float* __restrict__ rsum_g, float* __restrict__ oaccum,
    const int* __restrict__ aflagp)
{
    __shared__ __attribute__((aligned(16))) short xpanel[64 * DD];    // 16 KB
    __shared__ __attribute__((aligned(16))) float x2t[64];
    __shared__ __attribute__((aligned(16))) short ldsw[2][16 * 32];   // cold only

    const int tid = threadIdx.x;
    const int wid = tid >> 6, lane = tid & 63;
    const int lo = lane & 15, hi = lane >> 4;
    const int nb = blockIdx.x >> 8, mr = blockIdx.x & 255;
    const int mb = mr * 64;
    const int c0 = nb * 128 + wid * 64;

    // loop-invariant P fragments: lane holds P[n=c0+f*16+lo][k=(kf*4+hi)*8+j]
    short8 pf[4][4];
    float pc[4];
    #pragma unroll
    for (int f = 0; f < 4; ++f) {
        #pragma unroll
        for (int kf = 0; kf < 4; ++kf)
            pf[f][kf] = *(const short8*)(Pb + (size_t)(c0 + f * 16 + lo) * DD
                                            + (kf * 4 + hi) * 8);
        pc[f] = pcg[c0 + f * 16 + lo];
    }
    const int af = aflagp[0];

    // stage 64-row panel once. gll i covers rows i*8 + (tid>>4), 16B chunk
    // tid&15; source chunk pre-swizzled by row&15 = (i&1)*8 + (tid>>4):
    // two base pointers (i even / odd), dest linear = panel + tid*8 + i*1024.
    const int sr = tid >> 4, sch = tid & 15;
    const short* xsA = Xb + (size_t)(mb + sr) * DD + ((sch ^ sr) * 8);
    const short* xsB = Xb + (size_t)(mb + 8 + sr) * DD + ((sch ^ (8 + sr)) * 8);
    short* ld = xpanel + tid * 8;
    #pragma unroll
    for (int i = 0; i < 4; ++i) {
        __builtin_amdgcn_global_load_lds(
            (const __attribute__((address_space(1))) void*)(xsA + (size_t)i * 16 * DD),
            (__attribute__((address_space(3))) void*)(ld + (2 * i) * 1024), 16, 0, 0);
        __builtin_amdgcn_global_load_lds(
            (const __attribute__((address_space(1))) void*)(xsB + (size_t)i * 16 * DD),
            (__attribute__((address_space(3))) void*)(ld + (2 * i + 1) * 1024), 16, 0, 0);
    }
    if (tid < 64) x2t[tid] = x2g[mb + tid];
    __syncthreads();   // 2-wave barrier: panel + x2 ready

    float em[4] = {3.4e38f, 3.4e38f, 3.4e38f, 3.4e38f};

    #pragma unroll
    for (int sub = 0; sub < 4; ++sub) {
        short8 xf[4];
        #pragma unroll
        for (int kf = 0; kf < 4; ++kf)
            xf[kf] = *(const short8*)(xpanel + (sub * 16 + lo) * DD
                                      + (((kf * 4 + hi) ^ lo) * 8));
        f32x4 x2r = *(const f32x4*)(x2t + sub * 16 + hi * 4);

        f32x4 s0 = {0.f,0.f,0.f,0.f}, s1 = {0.f,0.f,0.f,0.f};
        f32x4 s2 = {0.f,0.f,0.f,0.f}, s3 = {0.f,0.f,0.f,0.f};
        #pragma unroll
        for (int kf = 0; kf < 4; ++kf) {
            s0 = __builtin_amdgcn_mfma_f32_16x16x32_bf16(xf[kf], pf[0][kf], s0, 0, 0, 0);
            s1 = __builtin_amdgcn_mfma_f32_16x16x32_bf16(xf[kf], pf[1][kf], s1, 0, 0, 0);
            s2 = __builtin_amdgcn_mfma_f32_16x16x32_bf16(xf[kf], pf[2][kf], s2, 0, 0, 0);
            s3 = __builtin_amdgcn_mfma_f32_16x16x32_bf16(xf[kf], pf[3][kf], s3, 0, 0, 0);
        }
        #pragma unroll
        for (int r = 0; r < 4; ++r) {
            float e0 = fmaf(s0[r], -2.f, x2r[r] + pc[0]);
            float e1 = fmaf(s1[r], -2.f, x2r[r] + pc[1]);
            float e2 = fmaf(s2[r], -2.f, x2r[r] + pc[2]);
            float e3 = fmaf(s3[r], -2.f, x2r[r] + pc[3]);
            em[0] = fminf(em[0], e0); em[1] = fminf(em[1], e1);
            em[2] = fminf(em[2], e2); em[3] = fminf(em[3], e3);
        }
    }

    const float emin = fminf(fminf(em[0], em[1]), fminf(em[2], em[3]));
    const int bad = (!(emin >= 0.f)) | af;
    if (__builtin_expect(__any(bad), 0)) {
        // ---- cold exact path: redo this wave's whole tile precisely ----
        const short* xrow = Xb + (size_t)(mb + lo) * DD;
        float p2v[4], cv[4];
        #pragma unroll
        for (int f = 0; f < 4; ++f) {
            p2v[f] = p2g[c0 + f * 16 + lo];
            cv[f]  = cg [c0 + f * 16 + lo];
        }
        #pragma unroll 1
        for (int t = 0; t < 4; ++t) {
            const int m0 = mb + t * 16;
            short8 xf[4];
            #pragma unroll
            for (int kf = 0; kf < 4; ++kf)
                xf[kf] = *(const short8*)(xrow + (size_t)t * 16 * DD + (kf * 4 + hi) * 8);
            f32x4 x2r = *(const f32x4*)(x2t + t * 16 + hi * 4);
            #pragma unroll
            for (int pr = 0; pr < 2; ++pr) {
                f32x4 s0 = {0.f,0.f,0.f,0.f}, s1 = {0.f,0.f,0.f,0.f};
                #pragma unroll
                for (int kf = 0; kf < 4; ++kf) {
                    s0 = __builtin_amdgcn_mfma_f32_16x16x32_bf16(xf[kf], pf[2*pr][kf],   s0, 0, 0, 0);
                    s1 = __builtin_amdgcn_mfma_f32_16x16x32_bf16(xf[kf], pf[2*pr+1][kf], s1, 0, 0, 0);
                }
                float w[8];
                int nz = 0;
                #pragma unroll
                for (int r = 0; r < 4; ++r) {
                    float d2a = fmaf(s0[r], -2.f, x2r[r] + p2v[2*pr]);
                    float d2b = fmaf(s1[r], -2.f, x2r[r] + p2v[2*pr+1]);
                    d2a = fmaxf(d2a, 0.f); d2b = fmaxf(d2b, 0.f);
                    float wa = exp2f(__builtin_amdgcn_sqrtf(d2a) * cv[2*pr]);
                    float wb = exp2f(__builtin_amdgcn_sqrtf(d2b) * cv[2*pr+1]);
                    w[r] = wa; w[4 + r] = wb;
                    nz |= (!(wa <= 0.f)) | (!(wb <= 0.f));   // NaN-safe
                }
                if (__any(nz) | af) {   // af: force PV so 0*NaN-V propagates
                    #pragma unroll
                    for (int r = 0; r < 4; ++r) {
                        float v = w[r] + w[4 + r];
                        v += __shfl_xor(v, 1); v += __shfl_xor(v, 2);
                        v += __shfl_xor(v, 4); v += __shfl_xor(v, 8);
                        if (lo == 0) atomicAdd(&rsum_g[m0 + hi * 4 + r], v);
                    }
                    #pragma unroll
                    for (int r = 0; r < 4; ++r) {
                        ldsw[wid][(hi * 4 + r) * 32 + lo]      = f2bf(w[r]);
                        ldsw[wid][(hi * 4 + r) * 32 + 16 + lo] = f2bf(w[4 + r]);
                    }
                    short8 wfr = *(const short8*)(&ldsw[wid][lo * 32 + hi * 8]);
                    #pragma unroll
                    for (int df = 0; df < 8; ++df) {
                        short8 vf = *(const short8*)(Vt + (size_t)(df * 16 + lo) * NTOT
                                                        + c0 + pr * 32 + hi * 8);
                        f32x4 of = {0.f,0.f,0.f,0.f};
                        of = __builtin_amdgcn_mfma_f32_16x16x32_bf16(wfr, vf, of, 0, 0, 0);
                        #pragma unroll
                        for (int r = 0; r < 4; ++r)
                            atomicAdd(&oaccum[(size_t)(m0 + hi * 4 + r) * DD + df * 16 + lo],
                                      of[r]);
                    }
                }
            }
        }
    }
}

// ---------------- normalize: only rows with nonzero rsum need work ----------
__global__ __launch_bounds__(256) void tide_norm(
    const float* __restrict__ rsum_g, float* __restrict__ outp)
{
    const int row = blockIdx.x * 256 + threadIdx.x;
    float s = rsum_g[row];
    if (s != 0.f) {
        float inv = 1.f / (s + 1e-8f);
        float* p = outp + (size_t)row * DD;
        #pragma unroll 4
        for (int j = 0; j < DD / 4; ++j) {
            f32x4 v = *(f32x4*)(p + j * 4);
            v[0] *= inv; v[1] *= inv; v[2] *= inv; v[3] *= inv;
            *(f32x4*)(p + j * 4) = v;
        }
    }
    // s == 0: out row already exact (0 / (0 + 1e-8) = 0, pre-zeroed)
}

extern "C" void kernel_launch(void* const* d_in, const int* in_sizes, int n_in,
                              void* d_out, int out_size, void* d_ws, size_t ws_size,
                              hipStream_t stream) {
    const float* x    = (const float*)d_in[0];  // [8,2048,128]
    const float* pos  = (const float*)d_in[1];  // [4096,128]
    const float* val  = (const float*)d_in[2];  // [4096,128]
    const float* temp = (const float*)d_in[3];  // [4096]
    float* out = (float*)d_out;

    char* ws = (char*)d_ws;
    short* Xb     = (short*)(ws);                    // 4 MB
    short* Pb     = (short*)(ws + 4194304);          // 1 MB
    short* Vt     = (short*)(ws + 5242880);          // 1 MB
    float* x2g    = (float*)(ws + 6291456);          // 64 KB
    float* p2g    = (float*)(ws + 6356992);          // 16 KB
    float* cg     = (float*)(ws + 6373376);          // 16 KB
    float* pcg    = (float*)(ws + 6389760);          // 16 KB
    float* rsum_g = (float*)(ws + 6406144);          // 64 KB
    int*   aflag  = (int*)  (ws + 6471680);          // 4 B

    hipLaunchKernelGGL(tide_prep, dim3(1796), dim3(256), 0, stream,
                       x, pos, val, temp, Xb, x2g, Pb, p2g, cg, pcg, Vt,
                       out, rsum_g, aflag);
    hipLaunchKernelGGL(tide_main, dim3(8192), dim3(128), 0, stream,
                       Xb, x2g, Pb, p2g, cg, pcg, Vt, rsum_g, out, aflag);
    hipLaunchKernelGGL(tide_norm, dim3(64), dim3(256), 0, stream,
                       rsum_g, out);
}

// Round 12
// 23.637 us; speedup vs baseline: 2.0357x; 2.0357x over previous
//
#include <hip/hip_runtime.h>
#include <hip/hip_bf16.h>

// RisingTideAttentionV2: out[m,:] = norm( exp(-||x_m - p_n|| / efft_n) ) @ V
// M=16384, N=4096, D=128. d2 = x2[m] + p2[n] - 2*dot(x_m,p_n). NEURON_SCALE=0.05125
//
// r12: MX-FP8 K=128 screen. w = expf(-dist/efft) is EXACTLY 0.0f when
// dist >= 104*efft; thr = 106.75*efft gives slack. Screen in fp8 e4m3 via
// mfma_scale_f32_16x16x128_f8f6f4 (scales = 1.0): quantization error bound
// |delta e| <= 0.27*Sum|x_i p_i| <= 27 given ||x||^2<=400, ||p||^2<=100
// (prep enforces; else aflag -> cold). pc[n] = p2 - thr^2 - 32 absorbs the
// margin: e_fp8 = x2 + pc - 2 s_fp8 >= 0 (all elems, wave vote at end)
// ==> d2_true > thr^2 ==> every weight exactly 0 ==> tile contributes 0 to
// numerator AND denominator ==> skip. Cold path (never taken for sane data)
// is layout-independent scalar f32 from the RAW inputs: exact reference math.

typedef __attribute__((ext_vector_type(4))) float f32x4;
typedef __attribute__((ext_vector_type(4))) int   i32x4;
typedef __attribute__((ext_vector_type(8))) int   i32x8;

#define MTOT 16384
#define NTOT 4096
#define DD   128

__device__ __forceinline__ i32x4 pack16_fp8(f32x4 a0, f32x4 a1, f32x4 a2, f32x4 a3) {
    int w0 = __builtin_amdgcn_cvt_pk_fp8_f32(a0[0], a0[1], 0, false);
    w0     = __builtin_amdgcn_cvt_pk_fp8_f32(a0[2], a0[3], w0, true);
    int w1 = __builtin_amdgcn_cvt_pk_fp8_f32(a1[0], a1[1], 0, false);
    w1     = __builtin_amdgcn_cvt_pk_fp8_f32(a1[2], a1[3], w1, true);
    int w2 = __builtin_amdgcn_cvt_pk_fp8_f32(a2[0], a2[1], 0, false);
    w2     = __builtin_amdgcn_cvt_pk_fp8_f32(a2[2], a2[3], w2, true);
    int w3 = __builtin_amdgcn_cvt_pk_fp8_f32(a3[0], a3[1], 0, false);
    w3     = __builtin_amdgcn_cvt_pk_fp8_f32(a3[2], a3[3], w3, true);
    return (i32x4){w0, w1, w2, w3};
}

// ---------------- prep ----------------
// blocks 0..511:    X -> fp8 Xb8 + x2g (32 rows each; 8 thr/row)
// blocks 512..639:  pos/temp -> Pb8, pcg; val finite-scan (32 n each)
// blocks 640..1151: zero d_out (16 KB each)
// blocks 1152..1155: zero rsum_g; block 1152 zeroes aflag
__global__ __launch_bounds__(256) void tide_prep(
    const float* __restrict__ x, const float* __restrict__ pos,
    const float* __restrict__ val, const float* __restrict__ temp,
    char* __restrict__ Xb8, float* __restrict__ x2g,
    char* __restrict__ Pb8, float* __restrict__ pcg,
    float* __restrict__ outz, float* __restrict__ rsz, int* __restrict__ aflag)
{
    const int bid = blockIdx.x, tid = threadIdx.x;
    if (bid < 512) {
        const int row = bid * 32 + (tid >> 3), seg = tid & 7;
        const float* src = x + (size_t)row * DD + seg * 16;
        f32x4 a0 = ((const f32x4*)src)[0];
        f32x4 a1 = ((const f32x4*)src)[1];
        f32x4 a2 = ((const f32x4*)src)[2];
        f32x4 a3 = ((const f32x4*)src)[3];
        *(i32x4*)(Xb8 + (size_t)row * DD + seg * 16) = pack16_fp8(a0, a1, a2, a3);
        float s = a0[0]*a0[0]+a0[1]*a0[1]+a0[2]*a0[2]+a0[3]*a0[3]
                + a1[0]*a1[0]+a1[1]*a1[1]+a1[2]*a1[2]+a1[3]*a1[3]
                + a2[0]*a2[0]+a2[1]*a2[1]+a2[2]*a2[2]+a2[3]*a2[3]
                + a3[0]*a3[0]+a3[1]*a3[1]+a3[2]*a3[2]+a3[3]*a3[3];
        s += __shfl_xor(s, 1); s += __shfl_xor(s, 2); s += __shfl_xor(s, 4);
        if (seg == 0) {
            x2g[row] = s;
            if (!(s <= 400.f)) atomicOr(aflag, 1);   // NaN/Inf/out-of-model
        }
    } else if (bid < 640) {
        const int n = (bid - 512) * 32 + (tid >> 3), seg = tid & 7;
        const float* ps = pos + (size_t)n * DD + seg * 16;
        f32x4 a0 = ((const f32x4*)ps)[0];
        f32x4 a1 = ((const f32x4*)ps)[1];
        f32x4 a2 = ((const f32x4*)ps)[2];
        f32x4 a3 = ((const f32x4*)ps)[3];
        *(i32x4*)(Pb8 + (size_t)n * DD + seg * 16) = pack16_fp8(a0, a1, a2, a3);
        float s = a0[0]*a0[0]+a0[1]*a0[1]+a0[2]*a0[2]+a0[3]*a0[3]
                + a1[0]*a1[0]+a1[1]*a1[1]+a1[2]*a1[2]+a1[3]*a1[3]
                + a2[0]*a2[0]+a2[1]*a2[1]+a2[2]*a2[2]+a2[3]*a2[3]
                + a3[0]*a3[0]+a3[1]*a3[1]+a3[2]*a3[2]+a3[3]*a3[3];
        s += __shfl_xor(s, 1); s += __shfl_xor(s, 2); s += __shfl_xor(s, 4);
        if (seg == 0) {
            if (!(s <= 100.f)) atomicOr(aflag, 1);
            float efft = (fabsf(temp[n]) + 0.1f) * 0.05125f;
            float thr = 106.7459f * efft;           // 154*ln2
            float pcv = s - thr * thr - 32.0f;      // margin 32 covers fp8 err
            pcg[n] = pcv;
            if (!isfinite(pcv)) atomicOr(aflag, 1);
        }
        // V finite-scan (reference: 0-weight x NaN-V still taints output)
        const float* vs = val + (size_t)n * DD + seg * 16;
        f32x4 b0 = ((const f32x4*)vs)[0];
        f32x4 b1 = ((const f32x4*)vs)[1];
        f32x4 b2 = ((const f32x4*)vs)[2];
        f32x4 b3 = ((const f32x4*)vs)[3];
        float vchk = fabsf(b0[0])+fabsf(b0[1])+fabsf(b0[2])+fabsf(b0[3])
                   + fabsf(b1[0])+fabsf(b1[1])+fabsf(b1[2])+fabsf(b1[3])
                   + fabsf(b2[0])+fabsf(b2[1])+fabsf(b2[2])+fabsf(b2[3])
                   + fabsf(b3[0])+fabsf(b3[1])+fabsf(b3[2])+fabsf(b3[3]);
        if (!isfinite(vchk)) atomicOr(aflag, 1);
    } else if (bid < 1152) {
        f32x4 z = {0.f, 0.f, 0.f, 0.f};
        float* dst = outz + (size_t)(bid - 640) * 4096;
        #pragma unroll
        for (int j = 0; j < 4; ++j)
            *(f32x4*)(dst + (size_t)(tid + 256 * j) * 4) = z;
    } else {
        f32x4 z = {0.f, 0.f, 0.f, 0.f};
        float* dst = rsz + (size_t)(bid - 1152) * 4096;
        #pragma unroll
        for (int j = 0; j < 4; ++j)
            *(f32x4*)(dst + (size_t)(tid + 256 * j) * 4) = z;
        if (bid == 1152 && tid == 0) aflag[0] = 0;
    }
}

// ---------------- main: fp8 K=128 screen ----------------
// grid = 2048: blockIdx = mc*16 + nb. Block: rows mc*128..+127, cols nb*256..+255.
// Wave w owns 64 cols; pf8 loop-invariant (32 VGPR). 16 KB fp8 X panel staged
// once via global_load_lds; 8 zero-sync subtiles of 2 ds_read + 4 MFMA + screen.
__global__ __launch_bounds__(256, 4) void tide_main(
    const char* __restrict__ Xb8, const float* __restrict__ x2g,
    const char* __restrict__ Pb8, const float* __restrict__ pcg,
    const float* __restrict__ x, const float* __restrict__ pos,
    const float* __restrict__ val, const float* __restrict__ temp,
    float* __restrict__ rsum_g, float* __restrict__ oaccum,
    const int* __restrict__ aflagp)
{
    __shared__ __attribute__((aligned(16))) char xpanel[128 * DD];  // 16 KB fp8
    __shared__ __attribute__((aligned(16))) float x2t[128];

    const int tid = threadIdx.x;
    const int wid = tid >> 6, lane = tid & 63;
    const int lo = lane & 15, hi = lane >> 4;
    const int nb = blockIdx.x & 15, mc = blockIdx.x >> 4;
    const int mb = mc * 128;
    const int c0 = nb * 256 + wid * 64;
    const int sc = 0x7F7F7F7F;   // e8m0 127 in every byte = scale 1.0

    // loop-invariant P fragments: lane holds P[n=c0+f*16+lo][k-bytes hi*32..+32]
    // (A and B use the same (hi,byte)->k placement, so any HW k-permutation
    //  cancels in the dot product; C layout is the m89-verified 16x16 map.)
    i32x8 pf8[4];
    float pc[4];
    #pragma unroll
    for (int f = 0; f < 4; ++f) {
        const char* pb = Pb8 + (size_t)(c0 + f * 16 + lo) * DD + hi * 32;
        i32x4 plo = *(const i32x4*)pb;
        i32x4 phi = *(const i32x4*)(pb + 16);
        pf8[f] = (i32x8){plo[0], plo[1], plo[2], plo[3],
                         phi[0], phi[1], phi[2], phi[3]};
        pc[f] = pcg[c0 + f * 16 + lo];
    }
    const int af = aflagp[0];

    // stage 128x128 fp8 panel once: thread t covers rows (t>>3)+32i, 16B chunk
    // t&7; source chunk pre-swizzled by row&7 ((t>>3)&7, i-invariant), linear dest.
    const int srow = tid >> 3, sch = tid & 7;
    const char* xs = Xb8 + (size_t)(mb + srow) * DD + ((sch ^ (srow & 7)) * 16);
    char* ld = xpanel + tid * 16;
    #pragma unroll
    for (int i = 0; i < 4; ++i)
        __builtin_amdgcn_global_load_lds(
            (const __attribute__((address_space(1))) void*)(xs + (size_t)i * 32 * DD),
            (__attribute__((address_space(3))) void*)(ld + i * 4096), 16, 0, 0);
    if (tid < 128) x2t[tid] = x2g[mb + tid];
    __syncthreads();   // the ONLY sync: panel + x2 ready

    float em[4] = {3.4e38f, 3.4e38f, 3.4e38f, 3.4e38f};

    #pragma unroll
    for (int t = 0; t < 8; ++t) {
        // A-frag: row lo of subtile, k-bytes hi*32..+32 (chunks hi*2, hi*2+1)
        const char* xb = xpanel + (t * 16 + lo) * DD;
        i32x4 xa = *(const i32x4*)(xb + (((hi * 2)     ^ (lo & 7)) * 16));
        i32x4 xc = *(const i32x4*)(xb + (((hi * 2 + 1) ^ (lo & 7)) * 16));
        i32x8 xf8 = (i32x8){xa[0], xa[1], xa[2], xa[3],
                            xc[0], xc[1], xc[2], xc[3]};
        f32x4 x2r = *(const f32x4*)(x2t + t * 16 + hi * 4);

        f32x4 s0 = __builtin_amdgcn_mfma_scale_f32_16x16x128_f8f6f4(
            xf8, pf8[0], (f32x4){0.f,0.f,0.f,0.f}, 0, 0, 0, sc, 0, sc);
        f32x4 s1 = __builtin_amdgcn_mfma_scale_f32_16x16x128_f8f6f4(
            xf8, pf8[1], (f32x4){0.f,0.f,0.f,0.f}, 0, 0, 0, sc, 0, sc);
        f32x4 s2 = __builtin_amdgcn_mfma_scale_f32_16x16x128_f8f6f4(
            xf8, pf8[2], (f32x4){0.f,0.f,0.f,0.f}, 0, 0, 0, sc, 0, sc);
        f32x4 s3 = __builtin_amdgcn_mfma_scale_f32_16x16x128_f8f6f4(
            xf8, pf8[3], (f32x4){0.f,0.f,0.f,0.f}, 0, 0, 0, sc, 0, sc);

        #pragma unroll
        for (int r = 0; r < 4; ++r) {
            float e0 = fmaf(s0[r], -2.f, x2r[r] + pc[0]);
            float e1 = fmaf(s1[r], -2.f, x2r[r] + pc[1]);
            float e2 = fmaf(s2[r], -2.f, x2r[r] + pc[2]);
            float e3 = fmaf(s3[r], -2.f, x2r[r] + pc[3]);
            em[0] = fminf(em[0], e0); em[1] = fminf(em[1], e1);
            em[2] = fminf(em[2], e2); em[3] = fminf(em[3], e3);
        }
    }

    const float emin = fminf(fminf(em[0], em[1]), fminf(em[2], em[3]));
    const int bad = (!(emin >= 0.f)) | af;
    if (__builtin_expect(__any(bad), 0)) {
        // ---- cold exact path: scalar f32 from RAW inputs (layout-free) ----
        #pragma unroll 1
        for (int t = 0; t < 8; ++t) {
            #pragma unroll 1
            for (int f = 0; f < 4; ++f) {
                const int n = c0 + f * 16 + lo;
                float efft = (fabsf(temp[n]) + 0.1f) * 0.05125f;
                #pragma unroll 1
                for (int r = 0; r < 4; ++r) {
                    const int m = mb + t * 16 + hi * 4 + r;
                    float dot = 0.f, p2 = 0.f;
                    const float* xr = x + (size_t)m * DD;
                    const float* pr = pos + (size_t)n * DD;
                    #pragma unroll 4
                    for (int k = 0; k < DD; k += 4) {
                        f32x4 xv = *(const f32x4*)(xr + k);
                        f32x4 pv = *(const f32x4*)(pr + k);
                        dot = fmaf(xv[0], pv[0], dot); dot = fmaf(xv[1], pv[1], dot);
                        dot = fmaf(xv[2], pv[2], dot); dot = fmaf(xv[3], pv[3], dot);
                        p2  = fmaf(pv[0], pv[0], p2);  p2  = fmaf(pv[1], pv[1], p2);
                        p2  = fmaf(pv[2], pv[2], p2);  p2  = fmaf(pv[3], pv[3], p2);
                    }
                    float d2 = fmaxf(x2t[m - mb] + p2 - 2.f * dot, 0.f);
                    float wv = expf(-__builtin_amdgcn_sqrtf(d2) / efft);
                    if (wv != 0.f || af) {   // af: propagate 0*NaN-V like ref
                        atomicAdd(&rsum_g[m], wv);
                        const float* vr = val + (size_t)n * DD;
                        #pragma unroll 1
                        for (int dcol = 0; dcol < DD; ++dcol)
                            atomicAdd(&oaccum[(size_t)m * DD + dcol], wv * vr[dcol]);
                    }
                }
            }
        }
    }
}

// ---------------- normalize: only rows with nonzero rsum need work ----------
__global__ __launch_bounds__(256) void tide_norm(
    const float* __restrict__ rsum_g, float* __restrict__ outp)
{
    const int row = blockIdx.x * 256 + threadIdx.x;
    float s = rsum_g[row];
    if (s != 0.f) {
        float inv = 1.f / (s + 1e-8f);
        float* p = outp + (size_t)row * DD;
        #pragma unroll 4
        for (int j = 0; j < DD / 4; ++j) {
            f32x4 v = *(f32x4*)(p + j * 4);
            v[0] *= inv; v[1] *= inv; v[2] *= inv; v[3] *= inv;
            *(f32x4*)(p + j * 4) = v;
        }
    }
    // s == 0: out row already exact (0 / (0 + 1e-8) = 0, pre-zeroed)
}

extern "C" void kernel_launch(void* const* d_in, const int* in_sizes, int n_in,
                              void* d_out, int out_size, void* d_ws, size_t ws_size,
                              hipStream_t stream) {
    const float* x    = (const float*)d_in[0];  // [8,2048,128]
    const float* pos  = (const float*)d_in[1];  // [4096,128]
    const float* val  = (const float*)d_in[2];  // [4096,128]
    const float* temp = (const float*)d_in[3];  // [4096]
    float* out = (float*)d_out;

    char* ws = (char*)d_ws;
    char*  Xb8    = ws;                              // 2 MB
    char*  Pb8    = ws + 2097152;                    // 512 KB
    float* x2g    = (float*)(ws + 2621440);          // 64 KB
    float* pcg    = (float*)(ws + 2686976);          // 16 KB
    float* rsum_g = (float*)(ws + 2703360);          // 64 KB
    int*   aflag  = (int*)  (ws + 2768896);          // 4 B

    hipLaunchKernelGGL(tide_prep, dim3(1156), dim3(256), 0, stream,
                       x, pos, val, temp, Xb8, x2g, Pb8, pcg, out, rsum_g, aflag);
    hipLaunchKernelGGL(tide_main, dim3(2048), dim3(256), 0, stream,
                       Xb8, x2g, Pb8, pcg, x, pos, val, temp, rsum_g, out, aflag);
    hipLaunchKernelGGL(tide_norm, dim3(64), dim3(256), 0, stream,
                       rsum_g, out);
}